// Round 15
// baseline (306.248 us; speedup 1.0000x reference)
//
#include <hip/hip_runtime.h>
#include <hip/hip_bf16.h>

#define EPS 1e-8f
#define LAMBDA 1e-3f
#define LN2PI_HALF 0.9189385332046727f

__device__ __forceinline__ float sigmoidf(float x) { return 1.f / (1.f + __expf(-x)); }

// ---------------------------------------------------------------------------
// 1) fused conv stem + primary caps v5 (validated)
// ---------------------------------------------------------------------------
__global__ __launch_bounds__(256) void stem_primary_kernel(
    const float* __restrict__ x, const float* __restrict__ w,
    const float* __restrict__ bias,
    const float* __restrict__ wp, const float* __restrict__ bp,
    const float* __restrict__ wa, const float* __restrict__ ba,
    float* __restrict__ pose, float* __restrict__ a) {
  __shared__ __align__(16) float wc_s[25][64];     // 6.4 KB
  __shared__ __align__(16) float wa_s[64][8];      // 2 KB
  __shared__ __align__(16) float bias_s[64];
  __shared__ __align__(16) float bp_s[128];
  __shared__ float ba_s[8];
  __shared__ float xs[5][63];
  __shared__ __align__(16) float ys_u[2][15][68];  // 8.16 KB

  int t = threadIdx.x;
  int oi = blockIdx.x % 30;
  int b  = blockIdx.x / 30;

  for (int q = t; q < 400;  q += 256) ((float4*)wc_s)[q] = ((const float4*)w)[q];
  for (int q = t; q < 128;  q += 256) ((float4*)wa_s)[q] = ((const float4*)wa)[q];
  if (t < 64) bias_s[t] = bias[t];
  if (t < 128) bp_s[t] = bp[t];
  if (t < 8) ba_s[t] = ba[t];
  for (int q = t; q < 315; q += 256) {
    int ki = q / 63, col = q % 63;
    xs[ki][col] = x[(b * 64 + 2 * oi + ki) * 64 + col];
  }
  __syncthreads();

  for (int q = t; q < 480; q += 256) {
    int pos = q >> 4, c4 = (q & 15) << 2;
    float4 s4 = *(const float4*)&bias_s[c4];
#pragma unroll
    for (int ki = 0; ki < 5; ++ki)
#pragma unroll
      for (int kj = 0; kj < 5; ++kj) {
        float xv = xs[ki][2 * pos + kj];
        const float4 wv = *(const float4*)&wc_s[ki * 5 + kj][c4];
        s4.x += xv * wv.x;
        s4.y += xv * wv.y;
        s4.z += xv * wv.z;
        s4.w += xv * wv.w;
      }
    s4.x = fmaxf(s4.x, 0.f);
    s4.y = fmaxf(s4.y, 0.f);
    s4.z = fmaxf(s4.z, 0.f);
    s4.w = fmaxf(s4.w, 0.f);
    *(float4*)&ys_u[pos & 1][pos >> 1][c4] = s4;
  }
  __syncthreads();

  int w_ = t >> 7, d = t & 127;
  float acc[15];
#pragma unroll
  for (int j = 0; j < 15; ++j) acc[j] = bp_s[d];
  const float* wpd = wp + d;
#pragma unroll 4
  for (int c4 = 0; c4 < 64; c4 += 4) {
    float w0 = wpd[(c4 + 0) * 128];
    float w1 = wpd[(c4 + 1) * 128];
    float w2 = wpd[(c4 + 2) * 128];
    float w3 = wpd[(c4 + 3) * 128];
#pragma unroll
    for (int j = 0; j < 15; ++j) {
      const float4 yv = *(const float4*)&ys_u[w_][j][c4];
      acc[j] += yv.x * w0 + yv.y * w1 + yv.z * w2 + yv.w * w3;
    }
  }
  size_t rowb = (size_t)(b * 30 + oi) * 30;
#pragma unroll
  for (int j = 0; j < 15; ++j)
    pose[(rowb + w_ + 2 * j) * 128 + d] = acc[j];

  if (t < 240) {
    int pos = t >> 3, jj = t & 7;
    float s = ba_s[jj];
#pragma unroll 8
    for (int c = 0; c < 64; ++c) s += ys_u[pos & 1][pos >> 1][c] * wa_s[c][jj];
    a[(rowb + pos) * 8 + jj] = sigmoidf(s);
  }
}

// ---------------------------------------------------------------------------
// 2) depthwise caps v6 (re-tiled; validated)
// ---------------------------------------------------------------------------
template <int K, int BC, int HIN, int WIN, int HOUT, int WOUT, int OIG, int NG>
__global__ __launch_bounds__(256) void dw_caps_kernel(
    const float* __restrict__ pose_in, const float* __restrict__ a_in,
    const float* __restrict__ Wt,
    const float* __restrict__ bu_p, const float* __restrict__ ba_p,
    float* __restrict__ pose_out, float* __restrict__ a_out) {
  constexpr int PAD = K / 2;
  constexpr int RA = (2 * (OIG - 1) + K < HIN) ? (2 * (OIG - 1) + K) : HIN;
  constexpr int TOT = OIG * WOUT * 16;
  constexpr int KM = (TOT + 255) / 256;
  __shared__ __align__(16) float tp[RA * WIN * 20];
  __shared__ float ta[RA * WIN];
  __shared__ __align__(16) float wt[K * K * 16];

  int t = threadIdx.x;
  int g = (NG > 1) ? (blockIdx.x % NG) : 0;
  int c = (blockIdx.x / NG) % BC;
  int b = blockIdx.x / (NG * BC);
  int oi_lo = g * OIG;
  int rlo = max(0, 2 * oi_lo - PAD);
  int rhi = min(HIN, 2 * (oi_lo + OIG - 1) - PAD + K);
  int nrows = rhi - rlo;

  for (int q = t; q < K * K * 16; q += 256) {
    int tap = q >> 4, lj = q & 15, l = lj >> 2, j = lj & 3;
    wt[tap * 16 + lj] = Wt[((size_t)tap * BC + c) * 16 + j * 4 + l];
  }
  for (int q = t; q < nrows * WIN; q += 256) {
    int row = q / WIN, col = q % WIN;
    ta[q] = a_in[((size_t)((b * HIN + rlo + row) * WIN + col)) * BC + c];
  }
  for (int q = t; q < nrows * WIN * 4; q += 256) {
    int quad = q & 3, pc = q >> 2;
    int row = pc / WIN, col = pc % WIN;
    const float4 src = *(const float4*)(pose_in +
        (((size_t)((b * HIN + rlo + row) * WIN + col)) * BC + c) * 16 + quad * 4);
    *(float4*)(tp + (row * WIN + col) * 20 + quad * 4) = src;
  }
  __syncthreads();

  const int p = t & 15;
  const int ip = p >> 2, l = p & 3;
  const float* wtl = wt + l * 4;

  int ih0[KM], iw0[KM];
  float rsum[KM], acc[KM], acc2[KM];
#pragma unroll
  for (int k = 0; k < KM; ++k) {
    int s = t + k * 256;
    int pr = s >> 4;
    int oj = pr % WOUT;
    int oi = oi_lo + pr / WOUT;
    ih0[k] = 2 * oi - PAD;
    iw0[k] = 2 * oj - PAD;
    rsum[k] = 0.f;
    acc[k] = 0.f;
    acc2[k] = 0.f;
  }

#pragma unroll 1
  for (int ki = 0; ki < K; ++ki) {
    int rb[KM];
    bool vk[KM];
#pragma unroll
    for (int k = 0; k < KM; ++k) {
      int ih = ih0[k] + ki;
      vk[k] = (t + k * 256 < TOT) && (ih >= 0) && (ih < HIN);
      rb[k] = (ih - rlo) * WIN;
    }
#pragma unroll
    for (int kj = 0; kj < K; ++kj) {
      const float4 wr = *(const float4*)(wtl + (ki * K + kj) * 16);
#pragma unroll
      for (int k = 0; k < KM; ++k) {
        if (!vk[k]) continue;
        int iw = iw0[k] + kj;
        if (iw < 0 || iw >= WIN) continue;
        int idx = rb[k] + iw;
        float ak = ta[idx];
        const float4 pm = *(const float4*)(tp + idx * 20 + ip * 4);
        float v = pm.x * wr.x + pm.y * wr.y + pm.z * wr.z + pm.w * wr.w;
        rsum[k] += ak;
        float av = ak * v;
        acc[k] += av;
        acc2[k] += av * v;
      }
    }
  }

#pragma unroll 1
  for (int k = 0; k < KM; ++k) {
    int s = t + k * 256;
    if (s >= TOT) break;
    int pr = s >> 4;
    int oj = pr % WOUT;
    int oi = oi_lo + pr / WOUT;
    float inv = 1.f / (rsum[k] + EPS);
    float mu = acc[k] * inv;
    float S = rsum[k] * inv;
    float sg = acc2[k] * inv - mu * mu * (2.f - S);
    sg = fmaxf(sg, 0.f) + EPS;
    float hl = 0.5f * __logf(sg);
    float ls = hl;
    ls += __shfl_xor(ls, 1, 64);
    ls += __shfl_xor(ls, 2, 64);
    ls += __shfl_xor(ls, 4, 64);
    ls += __shfl_xor(ls, 8, 64);

    size_t obase = ((size_t)(b * HOUT + oi) * WOUT + oj) * BC + c;
    pose_out[obase * 16 + p] = mu;
    if (p == 0) {
      float cost = rsum[k] * (16.f * bu_p[0] + ls);
      a_out[obase] = sigmoidf(LAMBDA * (ba_p[0] - cost));
    }
  }
}

// ---------------------------------------------------------------------------
// 3) cc1 co-op EM (validated-pass)
// ---------------------------------------------------------------------------
__global__ __launch_bounds__(256) void cc_em_coop8_kernel(
    const float* __restrict__ pose_in, const float* __restrict__ a_arr,
    const float* __restrict__ Wt,
    const float* __restrict__ bu_p, const float* __restrict__ ba_p,
    float* __restrict__ pose_out, float* __restrict__ a_out) {
  __shared__ float red_s[2][2][2][64 * 9];   // [buf][prob][wavehalf] 18.4 KB
  int t = threadIdx.x;
  int w = t >> 6, lane = t & 63;
  int prob = w >> 1, wh = w & 1;
  int c = lane >> 2, q = lane & 3;
  int n = blockIdx.x * 2 + prob;

  float ain[4], rw[4], v[4][4];
  const float* pbase = pose_in + (size_t)n * 128;   // 8 caps x 16
#pragma unroll
  for (int i = 0; i < 4; ++i) {
    int b = wh * 4 + i;
    ain[i] = a_arr[(size_t)n * 8 + b];
    rw[i] = (1.f / 16.f) * ain[i];
    const float4 pm = *(const float4*)(pbase + b * 16 + q * 4);
    const float* wr = Wt + (b * 16 + c) * 16;
    const float4 r0 = *(const float4*)(wr + 0);
    const float4 r1 = *(const float4*)(wr + 4);
    const float4 r2 = *(const float4*)(wr + 8);
    const float4 r3 = *(const float4*)(wr + 12);
    v[i][0] = pm.x * r0.x + pm.y * r1.x + pm.z * r2.x + pm.w * r3.x;
    v[i][1] = pm.x * r0.y + pm.y * r1.y + pm.z * r2.y + pm.w * r3.y;
    v[i][2] = pm.x * r0.z + pm.y * r1.z + pm.z * r2.z + pm.w * r3.z;
    v[i][3] = pm.x * r0.w + pm.y * r1.w + pm.z * r2.w + pm.w * r3.w;
  }
  float bu = bu_p[c], ba = ba_p[c];

  float mu[4], inv2[4], lsum = 0.f, ao = 0.f;
#pragma unroll 1
  for (int it = 0; it < 3; ++it) {
    float psA = 0.f, psV[4] = {0, 0, 0, 0}, psV2[4] = {0, 0, 0, 0};
#pragma unroll
    for (int i = 0; i < 4; ++i) {
      psA += rw[i];
#pragma unroll
      for (int l = 0; l < 4; ++l) {
        float rv = rw[i] * v[i][l];
        psV[l] += rv;
        psV2[l] += rv * v[i][l];
      }
    }
    {
      float* rs = &red_s[it & 1][prob][wh][lane * 9];
      rs[0] = psA;
#pragma unroll
      for (int l = 0; l < 4; ++l) { rs[1 + l] = psV[l]; rs[5 + l] = psV2[l]; }
    }
    __syncthreads();
    float sA = 0.f, sV[4] = {0, 0, 0, 0}, sV2[4] = {0, 0, 0, 0};
#pragma unroll
    for (int w2 = 0; w2 < 2; ++w2) {
      const float* rr = &red_s[it & 1][prob][w2][lane * 9];
      sA += rr[0];
#pragma unroll
      for (int l = 0; l < 4; ++l) { sV[l] += rr[1 + l]; sV2[l] += rr[5 + l]; }
    }
    float inv = 1.f / (sA + EPS);
    float S = sA * inv;
    lsum = 0.f;
#pragma unroll
    for (int l = 0; l < 4; ++l) {
      mu[l] = sV[l] * inv;
      float sg = sV2[l] * inv - mu[l] * mu[l] * (2.f - S) + EPS;
      sg = fmaxf(sg, EPS);
      inv2[l] = 0.5f / sg;
      lsum += 0.5f * __logf(sg);
    }
    lsum += __shfl_xor(lsum, 1, 64);
    lsum += __shfl_xor(lsum, 2, 64);
    float cost = sA * (16.f * bu + lsum);
    ao = sigmoidf(LAMBDA * (ba - cost));

    if (it < 2) {
      float term[4];
#pragma unroll
      for (int i = 0; i < 4; ++i) {
        float s = 0.f;
#pragma unroll
        for (int l = 0; l < 4; ++l) {
          float d = v[i][l] - mu[l];
          s += d * d * inv2[l];
        }
        term[i] = s;
      }
#pragma unroll
      for (int i = 0; i < 4; ++i) {
        term[i] += __shfl_xor(term[i], 1, 64);
        term[i] += __shfl_xor(term[i], 2, 64);
      }
      float basec = __logf(EPS + ao) - lsum - 16.f * LN2PI_HALF;
      float lnap[4], mx[4], Z[4];
#pragma unroll
      for (int i = 0; i < 4; ++i) { lnap[i] = basec - term[i]; mx[i] = lnap[i]; }
#pragma unroll
      for (int m = 4; m < 64; m <<= 1)
#pragma unroll
        for (int i = 0; i < 4; ++i) mx[i] = fmaxf(mx[i], __shfl_xor(mx[i], m, 64));
#pragma unroll
      for (int i = 0; i < 4; ++i) { lnap[i] = __expf(lnap[i] - mx[i]); Z[i] = lnap[i]; }
#pragma unroll
      for (int m = 4; m < 64; m <<= 1)
#pragma unroll
        for (int i = 0; i < 4; ++i) Z[i] += __shfl_xor(Z[i], m, 64);
#pragma unroll
      for (int i = 0; i < 4; ++i) rw[i] = lnap[i] / Z[i] * ain[i];
    }
  }
  if (wh == 0) {
    *(float4*)(pose_out + (size_t)n * 256 + c * 16 + q * 4) =
        make_float4(mu[0], mu[1], mu[2], mu[3]);
    if (q == 0) a_out[(size_t)n * 16 + c] = ao;
  }
}

// ---------------------------------------------------------------------------
// 3b) cc2 co-op EM (validated)
// ---------------------------------------------------------------------------
__global__ __launch_bounds__(256) void cc_em_coop16_kernel(
    const float* __restrict__ pose_in, const float* __restrict__ a_arr,
    const float* __restrict__ Wt,
    const float* __restrict__ bu_p, const float* __restrict__ ba_p,
    float* __restrict__ pose_out, float* __restrict__ a_out) {
  __shared__ float red_s[2][4][64 * 9];   // 18.4 KB
  int t = threadIdx.x;
  int w = t >> 6, lane = t & 63;
  int c = lane >> 2, q = lane & 3;
  int n = blockIdx.x;

  float ain[4], rw[4], v[4][4];
  const float* pbase = pose_in + (size_t)n * 256;
#pragma unroll
  for (int i = 0; i < 4; ++i) {
    int b = w * 4 + i;
    ain[i] = a_arr[(size_t)n * 16 + b];
    rw[i] = (1.f / 16.f) * ain[i];
    const float4 pm = *(const float4*)(pbase + b * 16 + q * 4);
    const float* wr = Wt + (b * 16 + c) * 16;
    const float4 r0 = *(const float4*)(wr + 0);
    const float4 r1 = *(const float4*)(wr + 4);
    const float4 r2 = *(const float4*)(wr + 8);
    const float4 r3 = *(const float4*)(wr + 12);
    v[i][0] = pm.x * r0.x + pm.y * r1.x + pm.z * r2.x + pm.w * r3.x;
    v[i][1] = pm.x * r0.y + pm.y * r1.y + pm.z * r2.y + pm.w * r3.y;
    v[i][2] = pm.x * r0.z + pm.y * r1.z + pm.z * r2.z + pm.w * r3.z;
    v[i][3] = pm.x * r0.w + pm.y * r1.w + pm.z * r2.w + pm.w * r3.w;
  }
  float bu = bu_p[c], ba = ba_p[c];

  float mu[4], inv2[4], lsum = 0.f, ao = 0.f;
#pragma unroll 1
  for (int it = 0; it < 3; ++it) {
    float psA = 0.f, psV[4] = {0, 0, 0, 0}, psV2[4] = {0, 0, 0, 0};
#pragma unroll
    for (int i = 0; i < 4; ++i) {
      psA += rw[i];
#pragma unroll
      for (int l = 0; l < 4; ++l) {
        float rv = rw[i] * v[i][l];
        psV[l] += rv;
        psV2[l] += rv * v[i][l];
      }
    }
    {
      float* rs = &red_s[it & 1][w][lane * 9];
      rs[0] = psA;
#pragma unroll
      for (int l = 0; l < 4; ++l) { rs[1 + l] = psV[l]; rs[5 + l] = psV2[l]; }
    }
    __syncthreads();
    float sA = 0.f, sV[4] = {0, 0, 0, 0}, sV2[4] = {0, 0, 0, 0};
#pragma unroll
    for (int w2 = 0; w2 < 4; ++w2) {
      const float* rr = &red_s[it & 1][w2][lane * 9];
      sA += rr[0];
#pragma unroll
      for (int l = 0; l < 4; ++l) { sV[l] += rr[1 + l]; sV2[l] += rr[5 + l]; }
    }
    float inv = 1.f / (sA + EPS);
    float S = sA * inv;
    lsum = 0.f;
#pragma unroll
    for (int l = 0; l < 4; ++l) {
      mu[l] = sV[l] * inv;
      float sg = sV2[l] * inv - mu[l] * mu[l] * (2.f - S) + EPS;
      sg = fmaxf(sg, EPS);
      inv2[l] = 0.5f / sg;
      lsum += 0.5f * __logf(sg);
    }
    lsum += __shfl_xor(lsum, 1, 64);
    lsum += __shfl_xor(lsum, 2, 64);
    float cost = sA * (16.f * bu + lsum);
    ao = sigmoidf(LAMBDA * (ba - cost));

    if (it < 2) {
      float term[4];
#pragma unroll
      for (int i = 0; i < 4; ++i) {
        float s = 0.f;
#pragma unroll
        for (int l = 0; l < 4; ++l) {
          float d = v[i][l] - mu[l];
          s += d * d * inv2[l];
        }
        term[i] = s;
      }
#pragma unroll
      for (int i = 0; i < 4; ++i) {
        term[i] += __shfl_xor(term[i], 1, 64);
        term[i] += __shfl_xor(term[i], 2, 64);
      }
      float basec = __logf(EPS + ao) - lsum - 16.f * LN2PI_HALF;
      float lnap[4], mx[4], Z[4];
#pragma unroll
      for (int i = 0; i < 4; ++i) { lnap[i] = basec - term[i]; mx[i] = lnap[i]; }
#pragma unroll
      for (int m = 4; m < 64; m <<= 1)
#pragma unroll
        for (int i = 0; i < 4; ++i) mx[i] = fmaxf(mx[i], __shfl_xor(mx[i], m, 64));
#pragma unroll
      for (int i = 0; i < 4; ++i) { lnap[i] = __expf(lnap[i] - mx[i]); Z[i] = lnap[i]; }
#pragma unroll
      for (int m = 4; m < 64; m <<= 1)
#pragma unroll
        for (int i = 0; i < 4; ++i) Z[i] += __shfl_xor(Z[i], m, 64);
#pragma unroll
      for (int i = 0; i < 4; ++i) rw[i] = lnap[i] / Z[i] * ain[i];
    }
  }
  if (w == 0) {
    *(float4*)(pose_out + (size_t)n * 256 + c * 16 + q * 4) =
        make_float4(mu[0], mu[1], mu[2], mu[3]);
    if (q == 0) a_out[(size_t)n * 16 + c] = ao;
  }
}

// ---------------------------------------------------------------------------
// 4a) class caps M-step (first iteration only; rw = 0.1*a5)
// ---------------------------------------------------------------------------
__global__ __launch_bounds__(256) void cls_m_kernel(
    const float* __restrict__ pose5, const float* __restrict__ a5,
    const float* __restrict__ W,
    const float* __restrict__ bu_p, const float* __restrict__ ba_p,
    float* __restrict__ mu_g, float* __restrict__ inv2_g,
    float* __restrict__ base_g) {
  int blk = blockIdx.x;                 // b*10 + c
  int c = blk % 10, b = blk / 10;
  int t = threadIdx.x;
  int lane = t & 63, wv = t >> 6;
  const float* pg = pose5 + (size_t)b * 16384;
  __shared__ float w_s[16][16];         // [jj][d]
  {
    int d = t & 15, jj = t >> 4;
    w_s[jj][d] = W[(d * 10 + c) * 16 + jj];
  }
  __syncthreads();
  const int d = t & 15;
  float wf[16];
#pragma unroll
  for (int jj = 0; jj < 16; ++jj) wf[jj] = w_s[jj][d];

  float sA = 0.f, sV[16], sV2[16];
#pragma unroll
  for (int p = 0; p < 16; ++p) { sV[p] = 0.f; sV2[p] = 0.f; }
#pragma unroll 1
  for (int rep = 0; rep < 4; ++rep) {
    int bi = rep * 256 + t;
    int pos = bi >> 4;
    float rw = 0.1f * a5[(size_t)b * 1024 + bi];
    float ci = (float)(pos >> 3) * 0.125f;
    float cj = (float)(pos & 7) * 0.125f;
    const float* pp = pg + pos * 256 + d * 16;
    float pmr[16];
#pragma unroll
    for (int q = 0; q < 16; ++q) pmr[q] = pp[q];
    sA += rw;
#pragma unroll
    for (int p = 0; p < 16; ++p) {
      int ip = p >> 2, l = p & 3;
      float v = pmr[ip * 4 + 0] * wf[0 * 4 + l] + pmr[ip * 4 + 1] * wf[1 * 4 + l]
              + pmr[ip * 4 + 2] * wf[2 * 4 + l] + pmr[ip * 4 + 3] * wf[3 * 4 + l];
      if (p == 0) v += ci;
      else if (p == 1) v += cj;
      float rv = rw * v;
      sV[p] += rv;
      sV2[p] += rv * v;
    }
  }
#pragma unroll
  for (int off = 1; off < 64; off <<= 1) {
    sA += __shfl_xor(sA, off, 64);
#pragma unroll
    for (int p = 0; p < 16; ++p) {
      sV[p]  += __shfl_xor(sV[p],  off, 64);
      sV2[p] += __shfl_xor(sV2[p], off, 64);
    }
  }
  __shared__ float red[4][36];
  if (lane == 0) {
    red[wv][0] = sA;
#pragma unroll
    for (int p = 0; p < 16; ++p) { red[wv][1 + p] = sV[p]; red[wv][17 + p] = sV2[p]; }
  }
  __syncthreads();
  if (t < 16) {
    int p = t;
    float sAf  = red[0][0] + red[1][0] + red[2][0] + red[3][0];
    float sVf  = red[0][1+p] + red[1][1+p] + red[2][1+p] + red[3][1+p];
    float sV2f = red[0][17+p] + red[1][17+p] + red[2][17+p] + red[3][17+p];
    float inv = 1.f / (sAf + EPS);
    float S = sAf * inv;
    float mu = sVf * inv;
    float sg = sV2f * inv - mu * mu * (2.f - S) + EPS;
    sg = fmaxf(sg, EPS);
    mu_g[blk * 16 + p] = mu;
    inv2_g[blk * 16 + p] = 0.5f / sg;
    float hl = 0.5f * __logf(sg);
    float lsum = hl;
    lsum += __shfl_xor(lsum, 1, 64);
    lsum += __shfl_xor(lsum, 2, 64);
    lsum += __shfl_xor(lsum, 4, 64);
    lsum += __shfl_xor(lsum, 8, 64);
    if (p == 0) {
      float cost = sAf * (16.f * bu_p[c] + lsum);
      float ao = sigmoidf(LAMBDA * (ba_p[c] - cost));
      base_g[blk] = __logf(EPS + ao) - lsum - 16.f * LN2PI_HALF;
    }
  }
}

// ---------------------------------------------------------------------------
// 4b) class caps FUSED E+M: each (b,c) block recomputes the E-step locally
//     (online softmax over 10 classes; votes for class c kept in registers)
//     and directly accumulates its M-step -- no Xbuf round-trip, 5 cls
//     dispatches -> 3. Stats double-buffered (in->o) to avoid same-dispatch
//     read/write races. E expressions verbatim except online softmax
//     (reassociation ~1e-6 << 2e-2 threshold).
// ---------------------------------------------------------------------------
__global__ __launch_bounds__(256) void cls_em_kernel(
    const float* __restrict__ pose5, const float* __restrict__ a5,
    const float* __restrict__ W,
    const float* __restrict__ bu_p, const float* __restrict__ ba_p,
    const float* __restrict__ mu_in, const float* __restrict__ inv2_in,
    const float* __restrict__ base_in,
    float* __restrict__ mu_o, float* __restrict__ inv2_o,
    float* __restrict__ base_o, float* __restrict__ out, int last) {
  int blk = blockIdx.x;                 // b*10 + c
  int c_m = blk % 10, b = blk / 10;
  int t = threadIdx.x;
  int lane = t & 63, wv = t >> 6;
  const float* pg = pose5 + (size_t)b * 16384;

  __shared__ float w2[10][16][16];      // [c][jj][d] 10 KB
  __shared__ float mu_s[160];
  __shared__ float inv2_s[160];
  __shared__ float base_s[10];
  __shared__ float red[4][36];

  for (int q = t; q < 2560; q += 256) {
    int dd = q & 15, jj = (q >> 4) & 15, c = q >> 8;
    w2[c][jj][dd] = W[(dd * 10 + c) * 16 + jj];
  }
  if (t < 160) { mu_s[t] = mu_in[b * 160 + t]; inv2_s[t] = inv2_in[b * 160 + t]; }
  if (t >= 160 && t < 170) base_s[t - 160] = base_in[b * 10 + (t - 160)];
  __syncthreads();

  const int d = t & 15;
  float sA = 0.f, sV[16], sV2[16];
#pragma unroll
  for (int p = 0; p < 16; ++p) { sV[p] = 0.f; sV2[p] = 0.f; }

#pragma unroll 1
  for (int rep = 0; rep < 4; ++rep) {
    int bi = rep * 256 + t;
    int pos = bi >> 4;
    float ci = (float)(pos >> 3) * 0.125f;
    float cj = (float)(pos & 7) * 0.125f;
    const float* pp = pg + pos * 256 + d * 16;
    float pmr[16];
#pragma unroll
    for (int q = 0; q < 16; ++q) pmr[q] = pp[q];
    float ain = a5[(size_t)b * 1024 + bi];

    // ---- E phase: online softmax over classes; keep votes for c_m ----
    float vc[16];
    float m_r = -1e30f, Z_r = 0.f, lnap_cm = 0.f;
#pragma unroll 1
    for (int c = 0; c < 10; ++c) {
      float wf[16];
#pragma unroll
      for (int jj = 0; jj < 16; ++jj) wf[jj] = w2[c][jj][d];
      float s = base_s[c];
#pragma unroll
      for (int p = 0; p < 16; ++p) {
        int ip = p >> 2, l = p & 3;
        float v = pmr[ip * 4 + 0] * wf[0 * 4 + l] + pmr[ip * 4 + 1] * wf[1 * 4 + l]
                + pmr[ip * 4 + 2] * wf[2 * 4 + l] + pmr[ip * 4 + 3] * wf[3 * 4 + l];
        if (p == 0) v += ci;
        else if (p == 1) v += cj;
        if (c == c_m) vc[p] = v;
        float dd2 = v - mu_s[c * 16 + p];
        s -= dd2 * dd2 * inv2_s[c * 16 + p];
      }
      if (c == c_m) lnap_cm = s;
      if (s > m_r) { Z_r = Z_r * __expf(m_r - s) + 1.f; m_r = s; }
      else Z_r += __expf(s - m_r);
    }
    float rw = __expf(lnap_cm - m_r) / Z_r * ain;

    // ---- M accumulation (same expressions as cls_m) ----
    sA += rw;
#pragma unroll
    for (int p = 0; p < 16; ++p) {
      float rv = rw * vc[p];
      sV[p] += rv;
      sV2[p] += rv * vc[p];
    }
  }

#pragma unroll
  for (int off = 1; off < 64; off <<= 1) {
    sA += __shfl_xor(sA, off, 64);
#pragma unroll
    for (int p = 0; p < 16; ++p) {
      sV[p]  += __shfl_xor(sV[p],  off, 64);
      sV2[p] += __shfl_xor(sV2[p], off, 64);
    }
  }
  if (lane == 0) {
    red[wv][0] = sA;
#pragma unroll
    for (int p = 0; p < 16; ++p) { red[wv][1 + p] = sV[p]; red[wv][17 + p] = sV2[p]; }
  }
  __syncthreads();
  if (t < 16) {
    int p = t;
    float sAf  = red[0][0] + red[1][0] + red[2][0] + red[3][0];
    float sVf  = red[0][1+p] + red[1][1+p] + red[2][1+p] + red[3][1+p];
    float sV2f = red[0][17+p] + red[1][17+p] + red[2][17+p] + red[3][17+p];
    float inv = 1.f / (sAf + EPS);
    float S = sAf * inv;
    float mu = sVf * inv;
    float sg = sV2f * inv - mu * mu * (2.f - S) + EPS;
    sg = fmaxf(sg, EPS);
    mu_o[blk * 16 + p] = mu;
    inv2_o[blk * 16 + p] = 0.5f / sg;
    float hl = 0.5f * __logf(sg);
    float lsum = hl;
    lsum += __shfl_xor(lsum, 1, 64);
    lsum += __shfl_xor(lsum, 2, 64);
    lsum += __shfl_xor(lsum, 4, 64);
    lsum += __shfl_xor(lsum, 8, 64);
    if (p == 0) {
      float cost = sAf * (16.f * bu_p[c_m] + lsum);
      float ao = sigmoidf(LAMBDA * (ba_p[c_m] - cost));
      base_o[blk] = __logf(EPS + ao) - lsum - 16.f * LN2PI_HALF;
      if (last) out[blk] = ao;
    }
  }
}

// ---------------------------------------------------------------------------
extern "C" void kernel_launch(void* const* d_in, const int* in_sizes, int n_in,
                              void* d_out, int out_size, void* d_ws, size_t ws_size,
                              hipStream_t stream) {
  const float* x       = (const float*)d_in[0];
  const float* conv1_w = (const float*)d_in[1];
  const float* conv1_b = (const float*)d_in[2];
  const float* pp_w    = (const float*)d_in[3];
  const float* pp_b    = (const float*)d_in[4];
  const float* pa_w    = (const float*)d_in[5];
  const float* pa_b    = (const float*)d_in[6];
  const float* dw1_w   = (const float*)d_in[7];
  const float* dw1_bu  = (const float*)d_in[8];
  const float* dw1_ba  = (const float*)d_in[9];
  const float* cc1_w   = (const float*)d_in[10];
  const float* cc1_bu  = (const float*)d_in[11];
  const float* cc1_ba  = (const float*)d_in[12];
  const float* dw2_w   = (const float*)d_in[13];
  const float* dw2_bu  = (const float*)d_in[14];
  const float* dw2_ba  = (const float*)d_in[15];
  const float* cc2_w   = (const float*)d_in[16];
  const float* cc2_bu  = (const float*)d_in[17];
  const float* cc2_ba  = (const float*)d_in[18];
  const float* cls_w   = (const float*)d_in[19];
  const float* cls_bu  = (const float*)d_in[20];
  const float* cls_ba  = (const float*)d_in[21];
  float* out = (float*)d_out;

  float* ws = (float*)d_ws;
  float* pose1 = ws;                  // 32*30*30*128
  float* a1    = ws + 3686400;        // 32*30*30*8
  float* pose2 = ws + 3916800;        // 32*15*15*128
  float* a2    = ws + 4838400;        // 32*15*15*8
  float* pose3 = ws;                  // 32*15*15*256 (aliases dead pose1)
  float* a3    = ws + 1843200;        // 32*15*15*16
  float* pose4 = ws + 1958400;        // 32*8*8*256
  float* a4    = ws + 2482688;        // 32*8*8*16
  float* pose5 = ws + 2515456;        // 32*8*8*256
  float* a5    = ws + 3039744;        // 32*8*8*16
  float* mu_gA  = ws + 3072512;       // 32*160
  float* inv2_gA= ws + 3077632;       // 32*160
  float* base_gA= ws + 3082752;       // 32*10
  float* mu_gB  = ws + 3083072;       // 32*160
  float* inv2_gB= ws + 3088192;       // 32*160
  float* base_gB= ws + 3093312;       // 32*10

  stem_primary_kernel<<<960, 256, 0, stream>>>(x, conv1_w, conv1_b,
                                               pp_w, pp_b, pa_w, pa_b, pose1, a1);
  dw_caps_kernel<7, 8, 30, 30, 15, 15, 3, 5><<<1280, 256, 0, stream>>>(
      pose1, a1, dw1_w, dw1_bu, dw1_ba, pose2, a2);
  cc_em_coop8_kernel<<<3600, 256, 0, stream>>>(pose2, a2, cc1_w, cc1_bu, cc1_ba,
                                               pose3, a3);
  dw_caps_kernel<5, 16, 15, 15, 8, 8, 2, 4><<<2048, 256, 0, stream>>>(
      pose3, a3, dw2_w, dw2_bu, dw2_ba, pose4, a4);
  cc_em_coop16_kernel<<<2048, 256, 0, stream>>>(pose4, a4, cc2_w, cc2_bu, cc2_ba,
                                                pose5, a5);
  cls_m_kernel<<<320, 256, 0, stream>>>(pose5, a5, cls_w, cls_bu, cls_ba,
                                        mu_gA, inv2_gA, base_gA);
  cls_em_kernel<<<320, 256, 0, stream>>>(pose5, a5, cls_w, cls_bu, cls_ba,
                                         mu_gA, inv2_gA, base_gA,
                                         mu_gB, inv2_gB, base_gB, out, 0);
  cls_em_kernel<<<320, 256, 0, stream>>>(pose5, a5, cls_w, cls_bu, cls_ba,
                                         mu_gB, inv2_gB, base_gB,
                                         mu_gA, inv2_gA, base_gA, out, 1);
}

// Round 16
// 250.980 us; speedup vs baseline: 1.2202x; 1.2202x over previous
//
#include <hip/hip_runtime.h>
#include <hip/hip_bf16.h>

#define EPS 1e-8f
#define LAMBDA 1e-3f
#define LN2PI_HALF 0.9189385332046727f

__device__ __forceinline__ float sigmoidf(float x) { return 1.f / (1.f + __expf(-x)); }

// ---------------------------------------------------------------------------
// 1) fused conv stem + primary caps v5 (wp from global; ~6us, validated)
// ---------------------------------------------------------------------------
__global__ __launch_bounds__(256) void stem_primary_kernel(
    const float* __restrict__ x, const float* __restrict__ w,
    const float* __restrict__ bias,
    const float* __restrict__ wp, const float* __restrict__ bp,
    const float* __restrict__ wa, const float* __restrict__ ba,
    float* __restrict__ pose, float* __restrict__ a) {
  __shared__ __align__(16) float wc_s[25][64];     // 6.4 KB
  __shared__ __align__(16) float wa_s[64][8];      // 2 KB
  __shared__ __align__(16) float bias_s[64];
  __shared__ __align__(16) float bp_s[128];
  __shared__ float ba_s[8];
  __shared__ float xs[5][63];
  __shared__ __align__(16) float ys_u[2][15][68];  // 8.16 KB

  int t = threadIdx.x;
  int oi = blockIdx.x % 30;
  int b  = blockIdx.x / 30;

  for (int q = t; q < 400;  q += 256) ((float4*)wc_s)[q] = ((const float4*)w)[q];
  for (int q = t; q < 128;  q += 256) ((float4*)wa_s)[q] = ((const float4*)wa)[q];
  if (t < 64) bias_s[t] = bias[t];
  if (t < 128) bp_s[t] = bp[t];
  if (t < 8) ba_s[t] = ba[t];
  for (int q = t; q < 315; q += 256) {
    int ki = q / 63, col = q % 63;
    xs[ki][col] = x[(b * 64 + 2 * oi + ki) * 64 + col];
  }
  __syncthreads();

  for (int q = t; q < 480; q += 256) {
    int pos = q >> 4, c4 = (q & 15) << 2;
    float4 s4 = *(const float4*)&bias_s[c4];
#pragma unroll
    for (int ki = 0; ki < 5; ++ki)
#pragma unroll
      for (int kj = 0; kj < 5; ++kj) {
        float xv = xs[ki][2 * pos + kj];
        const float4 wv = *(const float4*)&wc_s[ki * 5 + kj][c4];
        s4.x += xv * wv.x;
        s4.y += xv * wv.y;
        s4.z += xv * wv.z;
        s4.w += xv * wv.w;
      }
    s4.x = fmaxf(s4.x, 0.f);
    s4.y = fmaxf(s4.y, 0.f);
    s4.z = fmaxf(s4.z, 0.f);
    s4.w = fmaxf(s4.w, 0.f);
    *(float4*)&ys_u[pos & 1][pos >> 1][c4] = s4;
  }
  __syncthreads();

  int w_ = t >> 7, d = t & 127;
  float acc[15];
#pragma unroll
  for (int j = 0; j < 15; ++j) acc[j] = bp_s[d];
  const float* wpd = wp + d;
#pragma unroll 4
  for (int c4 = 0; c4 < 64; c4 += 4) {
    float w0 = wpd[(c4 + 0) * 128];
    float w1 = wpd[(c4 + 1) * 128];
    float w2 = wpd[(c4 + 2) * 128];
    float w3 = wpd[(c4 + 3) * 128];
#pragma unroll
    for (int j = 0; j < 15; ++j) {
      const float4 yv = *(const float4*)&ys_u[w_][j][c4];
      acc[j] += yv.x * w0 + yv.y * w1 + yv.z * w2 + yv.w * w3;
    }
  }
  size_t rowb = (size_t)(b * 30 + oi) * 30;
#pragma unroll
  for (int j = 0; j < 15; ++j)
    pose[(rowb + w_ + 2 * j) * 128 + d] = acc[j];

  if (t < 240) {
    int pos = t >> 3, jj = t & 7;
    float s = ba_s[jj];
#pragma unroll 8
    for (int c = 0; c < 64; ++c) s += ys_u[pos & 1][pos >> 1][c] * wa_s[c][jj];
    a[(rowb + pos) * 8 + jj] = sigmoidf(s);
  }
}

// ---------------------------------------------------------------------------
// 2) depthwise caps v6 (re-tiled; validated round 10)
// ---------------------------------------------------------------------------
template <int K, int BC, int HIN, int WIN, int HOUT, int WOUT, int OIG, int NG>
__global__ __launch_bounds__(256) void dw_caps_kernel(
    const float* __restrict__ pose_in, const float* __restrict__ a_in,
    const float* __restrict__ Wt,
    const float* __restrict__ bu_p, const float* __restrict__ ba_p,
    float* __restrict__ pose_out, float* __restrict__ a_out) {
  constexpr int PAD = K / 2;
  constexpr int RA = (2 * (OIG - 1) + K < HIN) ? (2 * (OIG - 1) + K) : HIN;
  constexpr int TOT = OIG * WOUT * 16;
  constexpr int KM = (TOT + 255) / 256;
  __shared__ __align__(16) float tp[RA * WIN * 20];
  __shared__ float ta[RA * WIN];
  __shared__ __align__(16) float wt[K * K * 16];

  int t = threadIdx.x;
  int g = (NG > 1) ? (blockIdx.x % NG) : 0;
  int c = (blockIdx.x / NG) % BC;
  int b = blockIdx.x / (NG * BC);
  int oi_lo = g * OIG;
  int rlo = max(0, 2 * oi_lo - PAD);
  int rhi = min(HIN, 2 * (oi_lo + OIG - 1) - PAD + K);
  int nrows = rhi - rlo;

  for (int q = t; q < K * K * 16; q += 256) {
    int tap = q >> 4, lj = q & 15, l = lj >> 2, j = lj & 3;
    wt[tap * 16 + lj] = Wt[((size_t)tap * BC + c) * 16 + j * 4 + l];
  }
  for (int q = t; q < nrows * WIN; q += 256) {
    int row = q / WIN, col = q % WIN;
    ta[q] = a_in[((size_t)((b * HIN + rlo + row) * WIN + col)) * BC + c];
  }
  for (int q = t; q < nrows * WIN * 4; q += 256) {
    int quad = q & 3, pc = q >> 2;
    int row = pc / WIN, col = pc % WIN;
    const float4 src = *(const float4*)(pose_in +
        (((size_t)((b * HIN + rlo + row) * WIN + col)) * BC + c) * 16 + quad * 4);
    *(float4*)(tp + (row * WIN + col) * 20 + quad * 4) = src;
  }
  __syncthreads();

  const int p = t & 15;
  const int ip = p >> 2, l = p & 3;
  const float* wtl = wt + l * 4;

  int ih0[KM], iw0[KM];
  float rsum[KM], acc[KM], acc2[KM];
#pragma unroll
  for (int k = 0; k < KM; ++k) {
    int s = t + k * 256;
    int pr = s >> 4;
    int oj = pr % WOUT;
    int oi = oi_lo + pr / WOUT;
    ih0[k] = 2 * oi - PAD;
    iw0[k] = 2 * oj - PAD;
    rsum[k] = 0.f;
    acc[k] = 0.f;
    acc2[k] = 0.f;
  }

#pragma unroll 1
  for (int ki = 0; ki < K; ++ki) {
    int rb[KM];
    bool vk[KM];
#pragma unroll
    for (int k = 0; k < KM; ++k) {
      int ih = ih0[k] + ki;
      vk[k] = (t + k * 256 < TOT) && (ih >= 0) && (ih < HIN);
      rb[k] = (ih - rlo) * WIN;
    }
#pragma unroll
    for (int kj = 0; kj < K; ++kj) {
      const float4 wr = *(const float4*)(wtl + (ki * K + kj) * 16);
#pragma unroll
      for (int k = 0; k < KM; ++k) {
        if (!vk[k]) continue;
        int iw = iw0[k] + kj;
        if (iw < 0 || iw >= WIN) continue;
        int idx = rb[k] + iw;
        float ak = ta[idx];
        const float4 pm = *(const float4*)(tp + idx * 20 + ip * 4);
        float v = pm.x * wr.x + pm.y * wr.y + pm.z * wr.z + pm.w * wr.w;
        rsum[k] += ak;
        float av = ak * v;
        acc[k] += av;
        acc2[k] += av * v;
      }
    }
  }

#pragma unroll 1
  for (int k = 0; k < KM; ++k) {
    int s = t + k * 256;
    if (s >= TOT) break;
    int pr = s >> 4;
    int oj = pr % WOUT;
    int oi = oi_lo + pr / WOUT;
    float inv = 1.f / (rsum[k] + EPS);
    float mu = acc[k] * inv;
    float S = rsum[k] * inv;
    float sg = acc2[k] * inv - mu * mu * (2.f - S);
    sg = fmaxf(sg, 0.f) + EPS;
    float hl = 0.5f * __logf(sg);
    float ls = hl;
    ls += __shfl_xor(ls, 1, 64);
    ls += __shfl_xor(ls, 2, 64);
    ls += __shfl_xor(ls, 4, 64);
    ls += __shfl_xor(ls, 8, 64);

    size_t obase = ((size_t)(b * HOUT + oi) * WOUT + oj) * BC + c;
    pose_out[obase * 16 + p] = mu;
    if (p == 0) {
      float cost = rsum[k] * (16.f * bu_p[0] + ls);
      a_out[obase] = sigmoidf(LAMBDA * (ba_p[0] - cost));
    }
  }
}

// ---------------------------------------------------------------------------
// 3) cc1 co-op EM (validated-pass)
// ---------------------------------------------------------------------------
__global__ __launch_bounds__(256) void cc_em_coop8_kernel(
    const float* __restrict__ pose_in, const float* __restrict__ a_arr,
    const float* __restrict__ Wt,
    const float* __restrict__ bu_p, const float* __restrict__ ba_p,
    float* __restrict__ pose_out, float* __restrict__ a_out) {
  __shared__ float red_s[2][2][2][64 * 9];   // [buf][prob][wavehalf] 18.4 KB
  int t = threadIdx.x;
  int w = t >> 6, lane = t & 63;
  int prob = w >> 1, wh = w & 1;
  int c = lane >> 2, q = lane & 3;
  int n = blockIdx.x * 2 + prob;

  float ain[4], rw[4], v[4][4];
  const float* pbase = pose_in + (size_t)n * 128;   // 8 caps x 16
#pragma unroll
  for (int i = 0; i < 4; ++i) {
    int b = wh * 4 + i;
    ain[i] = a_arr[(size_t)n * 8 + b];
    rw[i] = (1.f / 16.f) * ain[i];
    const float4 pm = *(const float4*)(pbase + b * 16 + q * 4);
    const float* wr = Wt + (b * 16 + c) * 16;
    const float4 r0 = *(const float4*)(wr + 0);
    const float4 r1 = *(const float4*)(wr + 4);
    const float4 r2 = *(const float4*)(wr + 8);
    const float4 r3 = *(const float4*)(wr + 12);
    v[i][0] = pm.x * r0.x + pm.y * r1.x + pm.z * r2.x + pm.w * r3.x;
    v[i][1] = pm.x * r0.y + pm.y * r1.y + pm.z * r2.y + pm.w * r3.y;
    v[i][2] = pm.x * r0.z + pm.y * r1.z + pm.z * r2.z + pm.w * r3.z;
    v[i][3] = pm.x * r0.w + pm.y * r1.w + pm.z * r2.w + pm.w * r3.w;
  }
  float bu = bu_p[c], ba = ba_p[c];

  float mu[4], inv2[4], lsum = 0.f, ao = 0.f;
#pragma unroll 1
  for (int it = 0; it < 3; ++it) {
    float psA = 0.f, psV[4] = {0, 0, 0, 0}, psV2[4] = {0, 0, 0, 0};
#pragma unroll
    for (int i = 0; i < 4; ++i) {
      psA += rw[i];
#pragma unroll
      for (int l = 0; l < 4; ++l) {
        float rv = rw[i] * v[i][l];
        psV[l] += rv;
        psV2[l] += rv * v[i][l];
      }
    }
    {
      float* rs = &red_s[it & 1][prob][wh][lane * 9];
      rs[0] = psA;
#pragma unroll
      for (int l = 0; l < 4; ++l) { rs[1 + l] = psV[l]; rs[5 + l] = psV2[l]; }
    }
    __syncthreads();
    float sA = 0.f, sV[4] = {0, 0, 0, 0}, sV2[4] = {0, 0, 0, 0};
#pragma unroll
    for (int w2 = 0; w2 < 2; ++w2) {
      const float* rr = &red_s[it & 1][prob][w2][lane * 9];
      sA += rr[0];
#pragma unroll
      for (int l = 0; l < 4; ++l) { sV[l] += rr[1 + l]; sV2[l] += rr[5 + l]; }
    }
    float inv = 1.f / (sA + EPS);
    float S = sA * inv;
    lsum = 0.f;
#pragma unroll
    for (int l = 0; l < 4; ++l) {
      mu[l] = sV[l] * inv;
      float sg = sV2[l] * inv - mu[l] * mu[l] * (2.f - S) + EPS;
      sg = fmaxf(sg, EPS);
      inv2[l] = 0.5f / sg;
      lsum += 0.5f * __logf(sg);
    }
    lsum += __shfl_xor(lsum, 1, 64);
    lsum += __shfl_xor(lsum, 2, 64);
    float cost = sA * (16.f * bu + lsum);
    ao = sigmoidf(LAMBDA * (ba - cost));

    if (it < 2) {
      float term[4];
#pragma unroll
      for (int i = 0; i < 4; ++i) {
        float s = 0.f;
#pragma unroll
        for (int l = 0; l < 4; ++l) {
          float d = v[i][l] - mu[l];
          s += d * d * inv2[l];
        }
        term[i] = s;
      }
#pragma unroll
      for (int i = 0; i < 4; ++i) {
        term[i] += __shfl_xor(term[i], 1, 64);
        term[i] += __shfl_xor(term[i], 2, 64);
      }
      float basec = __logf(EPS + ao) - lsum - 16.f * LN2PI_HALF;
      float lnap[4], mx[4], Z[4];
#pragma unroll
      for (int i = 0; i < 4; ++i) { lnap[i] = basec - term[i]; mx[i] = lnap[i]; }
#pragma unroll
      for (int m = 4; m < 64; m <<= 1)
#pragma unroll
        for (int i = 0; i < 4; ++i) mx[i] = fmaxf(mx[i], __shfl_xor(mx[i], m, 64));
#pragma unroll
      for (int i = 0; i < 4; ++i) { lnap[i] = __expf(lnap[i] - mx[i]); Z[i] = lnap[i]; }
#pragma unroll
      for (int m = 4; m < 64; m <<= 1)
#pragma unroll
        for (int i = 0; i < 4; ++i) Z[i] += __shfl_xor(Z[i], m, 64);
#pragma unroll
      for (int i = 0; i < 4; ++i) rw[i] = lnap[i] / Z[i] * ain[i];
    }
  }
  if (wh == 0) {
    *(float4*)(pose_out + (size_t)n * 256 + c * 16 + q * 4) =
        make_float4(mu[0], mu[1], mu[2], mu[3]);
    if (q == 0) a_out[(size_t)n * 16 + c] = ao;
  }
}

// ---------------------------------------------------------------------------
// 3b) cc2 co-op EM (validated)
// ---------------------------------------------------------------------------
__global__ __launch_bounds__(256) void cc_em_coop16_kernel(
    const float* __restrict__ pose_in, const float* __restrict__ a_arr,
    const float* __restrict__ Wt,
    const float* __restrict__ bu_p, const float* __restrict__ ba_p,
    float* __restrict__ pose_out, float* __restrict__ a_out) {
  __shared__ float red_s[2][4][64 * 9];   // 18.4 KB
  int t = threadIdx.x;
  int w = t >> 6, lane = t & 63;
  int c = lane >> 2, q = lane & 3;
  int n = blockIdx.x;

  float ain[4], rw[4], v[4][4];
  const float* pbase = pose_in + (size_t)n * 256;
#pragma unroll
  for (int i = 0; i < 4; ++i) {
    int b = w * 4 + i;
    ain[i] = a_arr[(size_t)n * 16 + b];
    rw[i] = (1.f / 16.f) * ain[i];
    const float4 pm = *(const float4*)(pbase + b * 16 + q * 4);
    const float* wr = Wt + (b * 16 + c) * 16;
    const float4 r0 = *(const float4*)(wr + 0);
    const float4 r1 = *(const float4*)(wr + 4);
    const float4 r2 = *(const float4*)(wr + 8);
    const float4 r3 = *(const float4*)(wr + 12);
    v[i][0] = pm.x * r0.x + pm.y * r1.x + pm.z * r2.x + pm.w * r3.x;
    v[i][1] = pm.x * r0.y + pm.y * r1.y + pm.z * r2.y + pm.w * r3.y;
    v[i][2] = pm.x * r0.z + pm.y * r1.z + pm.z * r2.z + pm.w * r3.z;
    v[i][3] = pm.x * r0.w + pm.y * r1.w + pm.z * r2.w + pm.w * r3.w;
  }
  float bu = bu_p[c], ba = ba_p[c];

  float mu[4], inv2[4], lsum = 0.f, ao = 0.f;
#pragma unroll 1
  for (int it = 0; it < 3; ++it) {
    float psA = 0.f, psV[4] = {0, 0, 0, 0}, psV2[4] = {0, 0, 0, 0};
#pragma unroll
    for (int i = 0; i < 4; ++i) {
      psA += rw[i];
#pragma unroll
      for (int l = 0; l < 4; ++l) {
        float rv = rw[i] * v[i][l];
        psV[l] += rv;
        psV2[l] += rv * v[i][l];
      }
    }
    {
      float* rs = &red_s[it & 1][w][lane * 9];
      rs[0] = psA;
#pragma unroll
      for (int l = 0; l < 4; ++l) { rs[1 + l] = psV[l]; rs[5 + l] = psV2[l]; }
    }
    __syncthreads();
    float sA = 0.f, sV[4] = {0, 0, 0, 0}, sV2[4] = {0, 0, 0, 0};
#pragma unroll
    for (int w2 = 0; w2 < 4; ++w2) {
      const float* rr = &red_s[it & 1][w2][lane * 9];
      sA += rr[0];
#pragma unroll
      for (int l = 0; l < 4; ++l) { sV[l] += rr[1 + l]; sV2[l] += rr[5 + l]; }
    }
    float inv = 1.f / (sA + EPS);
    float S = sA * inv;
    lsum = 0.f;
#pragma unroll
    for (int l = 0; l < 4; ++l) {
      mu[l] = sV[l] * inv;
      float sg = sV2[l] * inv - mu[l] * mu[l] * (2.f - S) + EPS;
      sg = fmaxf(sg, EPS);
      inv2[l] = 0.5f / sg;
      lsum += 0.5f * __logf(sg);
    }
    lsum += __shfl_xor(lsum, 1, 64);
    lsum += __shfl_xor(lsum, 2, 64);
    float cost = sA * (16.f * bu + lsum);
    ao = sigmoidf(LAMBDA * (ba - cost));

    if (it < 2) {
      float term[4];
#pragma unroll
      for (int i = 0; i < 4; ++i) {
        float s = 0.f;
#pragma unroll
        for (int l = 0; l < 4; ++l) {
          float d = v[i][l] - mu[l];
          s += d * d * inv2[l];
        }
        term[i] = s;
      }
#pragma unroll
      for (int i = 0; i < 4; ++i) {
        term[i] += __shfl_xor(term[i], 1, 64);
        term[i] += __shfl_xor(term[i], 2, 64);
      }
      float basec = __logf(EPS + ao) - lsum - 16.f * LN2PI_HALF;
      float lnap[4], mx[4], Z[4];
#pragma unroll
      for (int i = 0; i < 4; ++i) { lnap[i] = basec - term[i]; mx[i] = lnap[i]; }
#pragma unroll
      for (int m = 4; m < 64; m <<= 1)
#pragma unroll
        for (int i = 0; i < 4; ++i) mx[i] = fmaxf(mx[i], __shfl_xor(mx[i], m, 64));
#pragma unroll
      for (int i = 0; i < 4; ++i) { lnap[i] = __expf(lnap[i] - mx[i]); Z[i] = lnap[i]; }
#pragma unroll
      for (int m = 4; m < 64; m <<= 1)
#pragma unroll
        for (int i = 0; i < 4; ++i) Z[i] += __shfl_xor(Z[i], m, 64);
#pragma unroll
      for (int i = 0; i < 4; ++i) rw[i] = lnap[i] / Z[i] * ain[i];
    }
  }
  if (w == 0) {
    *(float4*)(pose_out + (size_t)n * 256 + c * 16 + q * 4) =
        make_float4(mu[0], mu[1], mu[2], mu[3]);
    if (q == 0) a_out[(size_t)n * 16 + c] = ao;
  }
}

// ---------------------------------------------------------------------------
// 4a) class caps M-step (round-10 validated)
// ---------------------------------------------------------------------------
__global__ __launch_bounds__(256) void cls_m_kernel(
    const float* __restrict__ pose5, const float* __restrict__ a5,
    const float* __restrict__ X, const float* __restrict__ W,
    const float* __restrict__ bu_p, const float* __restrict__ ba_p,
    float* __restrict__ mu_g, float* __restrict__ inv2_g,
    float* __restrict__ base_g, float* __restrict__ out,
    int first, int last) {
  int blk = blockIdx.x;                 // b*10 + c
  int c = blk % 10, b = blk / 10;
  int t = threadIdx.x;
  int lane = t & 63, wv = t >> 6;
  const float* pg = pose5 + (size_t)b * 16384;
  __shared__ float w_s[16][16];         // [jj][d]
  {
    int d = t & 15, jj = t >> 4;
    w_s[jj][d] = W[(d * 10 + c) * 16 + jj];
  }
  __syncthreads();
  const int d = t & 15;
  float wf[16];
#pragma unroll
  for (int jj = 0; jj < 16; ++jj) wf[jj] = w_s[jj][d];

  float sA = 0.f, sV[16], sV2[16];
#pragma unroll
  for (int p = 0; p < 16; ++p) { sV[p] = 0.f; sV2[p] = 0.f; }
#pragma unroll 1
  for (int rep = 0; rep < 4; ++rep) {
    int bi = rep * 256 + t;
    int pos = bi >> 4;
    float rw = first ? 0.1f * a5[(size_t)b * 1024 + bi]
                     : X[(size_t)blk * 1024 + bi];
    float ci = (float)(pos >> 3) * 0.125f;
    float cj = (float)(pos & 7) * 0.125f;
    const float* pp = pg + pos * 256 + d * 16;
    float pmr[16];
#pragma unroll
    for (int q = 0; q < 16; ++q) pmr[q] = pp[q];
    sA += rw;
#pragma unroll
    for (int p = 0; p < 16; ++p) {
      int ip = p >> 2, l = p & 3;
      float v = pmr[ip * 4 + 0] * wf[0 * 4 + l] + pmr[ip * 4 + 1] * wf[1 * 4 + l]
              + pmr[ip * 4 + 2] * wf[2 * 4 + l] + pmr[ip * 4 + 3] * wf[3 * 4 + l];
      if (p == 0) v += ci;
      else if (p == 1) v += cj;
      float rv = rw * v;
      sV[p] += rv;
      sV2[p] += rv * v;
    }
  }
#pragma unroll
  for (int off = 1; off < 64; off <<= 1) {
    sA += __shfl_xor(sA, off, 64);
#pragma unroll
    for (int p = 0; p < 16; ++p) {
      sV[p]  += __shfl_xor(sV[p],  off, 64);
      sV2[p] += __shfl_xor(sV2[p], off, 64);
    }
  }
  __shared__ float red[4][36];
  if (lane == 0) {
    red[wv][0] = sA;
#pragma unroll
    for (int p = 0; p < 16; ++p) { red[wv][1 + p] = sV[p]; red[wv][17 + p] = sV2[p]; }
  }
  __syncthreads();
  if (t < 16) {
    int p = t;
    float sAf  = red[0][0] + red[1][0] + red[2][0] + red[3][0];
    float sVf  = red[0][1+p] + red[1][1+p] + red[2][1+p] + red[3][1+p];
    float sV2f = red[0][17+p] + red[1][17+p] + red[2][17+p] + red[3][17+p];
    float inv = 1.f / (sAf + EPS);
    float S = sAf * inv;
    float mu = sVf * inv;
    float sg = sV2f * inv - mu * mu * (2.f - S) + EPS;
    sg = fmaxf(sg, EPS);
    mu_g[blk * 16 + p] = mu;
    inv2_g[blk * 16 + p] = 0.5f / sg;
    float hl = 0.5f * __logf(sg);
    float lsum = hl;
    lsum += __shfl_xor(lsum, 1, 64);
    lsum += __shfl_xor(lsum, 2, 64);
    lsum += __shfl_xor(lsum, 4, 64);
    lsum += __shfl_xor(lsum, 8, 64);
    if (p == 0) {
      float cost = sAf * (16.f * bu_p[c] + lsum);
      float ao = sigmoidf(LAMBDA * (ba_p[c] - cost));
      base_g[blk] = __logf(EPS + ao) - lsum - 16.f * LN2PI_HALF;
      if (last) out[blk] = ao;
    }
  }
}

// ---------------------------------------------------------------------------
// 4b) class caps E-step v2 (round-10 validated: 4 blocks/image x 256 thr)
// ---------------------------------------------------------------------------
__global__ __launch_bounds__(256) void cls_e_kernel(
    const float* __restrict__ pose5, const float* __restrict__ a5,
    const float* __restrict__ W,
    const float* __restrict__ mu_g, const float* __restrict__ inv2_g,
    const float* __restrict__ base_g, float* __restrict__ X) {
  int b = blockIdx.x >> 2;
  int t = threadIdx.x;
  int bi = ((blockIdx.x & 3) << 8) + t;
  const float* pg = pose5 + (size_t)b * 16384;
  __shared__ float w2[10][16][16];      // [c][jj][d]
  __shared__ float mu_s[160];
  __shared__ float inv2_s[160];
  __shared__ float base_s[10];
  for (int q = t; q < 2560; q += 256) {
    int dd = q & 15, jj = (q >> 4) & 15, c = q >> 8;
    w2[c][jj][dd] = W[(dd * 10 + c) * 16 + jj];
  }
  if (t < 160) { mu_s[t] = mu_g[b * 160 + t]; inv2_s[t] = inv2_g[b * 160 + t]; }
  if (t >= 160 && t < 170) base_s[t - 160] = base_g[b * 10 + (t - 160)];
  __syncthreads();

  int pos = bi >> 4, d2 = bi & 15;
  float ci = (float)(pos >> 3) * 0.125f;
  float cj = (float)(pos & 7) * 0.125f;
  const float* pp = pg + pos * 256 + d2 * 16;
  float pmr[16];
#pragma unroll
  for (int q = 0; q < 16; ++q) pmr[q] = pp[q];
  float lnap[10];
#pragma unroll 1
  for (int c = 0; c < 10; ++c) {
    float wf[16];
#pragma unroll
    for (int jj = 0; jj < 16; ++jj) wf[jj] = w2[c][jj][d2];
    float s = base_s[c];
#pragma unroll
    for (int p = 0; p < 16; ++p) {
      int ip = p >> 2, l = p & 3;
      float v = pmr[ip * 4 + 0] * wf[0 * 4 + l] + pmr[ip * 4 + 1] * wf[1 * 4 + l]
              + pmr[ip * 4 + 2] * wf[2 * 4 + l] + pmr[ip * 4 + 3] * wf[3 * 4 + l];
      if (p == 0) v += ci;
      else if (p == 1) v += cj;
      float dd = v - mu_s[c * 16 + p];
      s -= dd * dd * inv2_s[c * 16 + p];
    }
    lnap[c] = s;
  }
  float m = -1e30f;
#pragma unroll
  for (int c = 0; c < 10; ++c) m = fmaxf(m, lnap[c]);
  float Z = 0.f;
  float ex[10];
#pragma unroll
  for (int c = 0; c < 10; ++c) { ex[c] = __expf(lnap[c] - m); Z += ex[c]; }
  float invZ = a5[(size_t)b * 1024 + bi] / Z;
#pragma unroll
  for (int c = 0; c < 10; ++c) X[((size_t)(b * 10 + c)) * 1024 + bi] = ex[c] * invZ;
}

// ---------------------------------------------------------------------------
extern "C" void kernel_launch(void* const* d_in, const int* in_sizes, int n_in,
                              void* d_out, int out_size, void* d_ws, size_t ws_size,
                              hipStream_t stream) {
  const float* x       = (const float*)d_in[0];
  const float* conv1_w = (const float*)d_in[1];
  const float* conv1_b = (const float*)d_in[2];
  const float* pp_w    = (const float*)d_in[3];
  const float* pp_b    = (const float*)d_in[4];
  const float* pa_w    = (const float*)d_in[5];
  const float* pa_b    = (const float*)d_in[6];
  const float* dw1_w   = (const float*)d_in[7];
  const float* dw1_bu  = (const float*)d_in[8];
  const float* dw1_ba  = (const float*)d_in[9];
  const float* cc1_w   = (const float*)d_in[10];
  const float* cc1_bu  = (const float*)d_in[11];
  const float* cc1_ba  = (const float*)d_in[12];
  const float* dw2_w   = (const float*)d_in[13];
  const float* dw2_bu  = (const float*)d_in[14];
  const float* dw2_ba  = (const float*)d_in[15];
  const float* cc2_w   = (const float*)d_in[16];
  const float* cc2_bu  = (const float*)d_in[17];
  const float* cc2_ba  = (const float*)d_in[18];
  const float* cls_w   = (const float*)d_in[19];
  const float* cls_bu  = (const float*)d_in[20];
  const float* cls_ba  = (const float*)d_in[21];
  float* out = (float*)d_out;

  float* ws = (float*)d_ws;
  float* pose1 = ws;                  // 32*30*30*128
  float* a1    = ws + 3686400;        // 32*30*30*8
  float* pose2 = ws + 3916800;        // 32*15*15*128
  float* a2    = ws + 4838400;        // 32*15*15*8
  float* pose3 = ws;                  // 32*15*15*256 (aliases dead pose1)
  float* a3    = ws + 1843200;        // 32*15*15*16
  float* pose4 = ws + 1958400;        // 32*8*8*256
  float* a4    = ws + 2482688;        // 32*8*8*16
  float* pose5 = ws + 2515456;        // 32*8*8*256
  float* a5    = ws + 3039744;        // 32*8*8*16
  float* Xbuf  = ws + 3072512;        // 32*10*1024
  float* mu_g  = ws + 3400192;        // 32*160
  float* inv2_g= ws + 3405312;        // 32*160
  float* base_g= ws + 3410432;        // 32*10

  stem_primary_kernel<<<960, 256, 0, stream>>>(x, conv1_w, conv1_b,
                                               pp_w, pp_b, pa_w, pa_b, pose1, a1);
  dw_caps_kernel<7, 8, 30, 30, 15, 15, 3, 5><<<1280, 256, 0, stream>>>(
      pose1, a1, dw1_w, dw1_bu, dw1_ba, pose2, a2);
  cc_em_coop8_kernel<<<3600, 256, 0, stream>>>(pose2, a2, cc1_w, cc1_bu, cc1_ba,
                                               pose3, a3);
  dw_caps_kernel<5, 16, 15, 15, 8, 8, 2, 4><<<2048, 256, 0, stream>>>(
      pose3, a3, dw2_w, dw2_bu, dw2_ba, pose4, a4);
  cc_em_coop16_kernel<<<2048, 256, 0, stream>>>(pose4, a4, cc2_w, cc2_bu, cc2_ba,
                                                pose5, a5);
  cls_m_kernel<<<320, 256, 0, stream>>>(pose5, a5, Xbuf, cls_w, cls_bu, cls_ba,
                                        mu_g, inv2_g, base_g, out, 1, 0);
  cls_e_kernel<<<128, 256, 0, stream>>>(pose5, a5, cls_w, mu_g, inv2_g, base_g, Xbuf);
  cls_m_kernel<<<320, 256, 0, stream>>>(pose5, a5, Xbuf, cls_w, cls_bu, cls_ba,
                                        mu_g, inv2_g, base_g, out, 0, 0);
  cls_e_kernel<<<128, 256, 0, stream>>>(pose5, a5, cls_w, mu_g, inv2_g, base_g, Xbuf);
  cls_m_kernel<<<320, 256, 0, stream>>>(pose5, a5, Xbuf, cls_w, cls_bu, cls_ba,
                                        mu_g, inv2_g, base_g, out, 0, 1);
}

// Round 17
// 247.042 us; speedup vs baseline: 1.2397x; 1.0159x over previous
//
#include <hip/hip_runtime.h>
#include <hip/hip_bf16.h>

#define EPS 1e-8f
#define LAMBDA 1e-3f
#define LN2PI_HALF 0.9189385332046727f

__device__ __forceinline__ float sigmoidf(float x) { return 1.f / (1.f + __expf(-x)); }

// ---------------------------------------------------------------------------
// 1) fused conv stem + primary caps v6 — pose1/a1 now written CHANNEL-MAJOR
//    (pose1T[c][b*900+pos][16], a1T[c][b*900+pos]) so dw1's per-channel
//    staging reads are fully coalesced. Values bit-identical to v5.
// ---------------------------------------------------------------------------
__global__ __launch_bounds__(256) void stem_primary_kernel(
    const float* __restrict__ x, const float* __restrict__ w,
    const float* __restrict__ bias,
    const float* __restrict__ wp, const float* __restrict__ bp,
    const float* __restrict__ wa, const float* __restrict__ ba,
    float* __restrict__ pose, float* __restrict__ a) {
  __shared__ __align__(16) float wc_s[25][64];     // 6.4 KB
  __shared__ __align__(16) float wa_s[64][8];      // 2 KB
  __shared__ __align__(16) float bias_s[64];
  __shared__ __align__(16) float bp_s[128];
  __shared__ float ba_s[8];
  __shared__ float xs[5][63];
  __shared__ __align__(16) float ys_u[2][15][68];  // 8.16 KB

  int t = threadIdx.x;
  int oi = blockIdx.x % 30;
  int b  = blockIdx.x / 30;

  for (int q = t; q < 400;  q += 256) ((float4*)wc_s)[q] = ((const float4*)w)[q];
  for (int q = t; q < 128;  q += 256) ((float4*)wa_s)[q] = ((const float4*)wa)[q];
  if (t < 64) bias_s[t] = bias[t];
  if (t < 128) bp_s[t] = bp[t];
  if (t < 8) ba_s[t] = ba[t];
  for (int q = t; q < 315; q += 256) {
    int ki = q / 63, col = q % 63;
    xs[ki][col] = x[(b * 64 + 2 * oi + ki) * 64 + col];
  }
  __syncthreads();

  for (int q = t; q < 480; q += 256) {
    int pos = q >> 4, c4 = (q & 15) << 2;
    float4 s4 = *(const float4*)&bias_s[c4];
#pragma unroll
    for (int ki = 0; ki < 5; ++ki)
#pragma unroll
      for (int kj = 0; kj < 5; ++kj) {
        float xv = xs[ki][2 * pos + kj];
        const float4 wv = *(const float4*)&wc_s[ki * 5 + kj][c4];
        s4.x += xv * wv.x;
        s4.y += xv * wv.y;
        s4.z += xv * wv.z;
        s4.w += xv * wv.w;
      }
    s4.x = fmaxf(s4.x, 0.f);
    s4.y = fmaxf(s4.y, 0.f);
    s4.z = fmaxf(s4.z, 0.f);
    s4.w = fmaxf(s4.w, 0.f);
    *(float4*)&ys_u[pos & 1][pos >> 1][c4] = s4;
  }
  __syncthreads();

  int w_ = t >> 7, d = t & 127;
  float acc[15];
#pragma unroll
  for (int j = 0; j < 15; ++j) acc[j] = bp_s[d];
  const float* wpd = wp + d;
#pragma unroll 4
  for (int c4 = 0; c4 < 64; c4 += 4) {
    float w0 = wpd[(c4 + 0) * 128];
    float w1 = wpd[(c4 + 1) * 128];
    float w2 = wpd[(c4 + 2) * 128];
    float w3 = wpd[(c4 + 3) * 128];
#pragma unroll
    for (int j = 0; j < 15; ++j) {
      const float4 yv = *(const float4*)&ys_u[w_][j][c4];
      acc[j] += yv.x * w0 + yv.y * w1 + yv.z * w2 + yv.w * w3;
    }
  }
  size_t rowb = (size_t)(b * 30 + oi) * 30;
  // channel-major pose write: pose[((c*28800) + rowb + w_ + 2j)*16 + p]
  int cch = d >> 4, p = d & 15;
#pragma unroll
  for (int j = 0; j < 15; ++j)
    pose[((size_t)cch * 28800 + rowb + w_ + 2 * j) * 16 + p] = acc[j];

  if (t < 240) {
    int pos = t >> 3, jj = t & 7;
    float s = ba_s[jj];
#pragma unroll 8
    for (int c = 0; c < 64; ++c) s += ys_u[pos & 1][pos >> 1][c] * wa_s[c][jj];
    a[(size_t)jj * 28800 + rowb + pos] = sigmoidf(s);
  }
}

// ---------------------------------------------------------------------------
// 2) depthwise caps v7 — template flag TIN selects channel-major input
//    (dw1: true, reads stem's pose1T/a1T coalesced) or position-major
//    (dw2: false, unchanged). Compute identical.
// ---------------------------------------------------------------------------
template <int K, int BC, int HIN, int WIN, int HOUT, int WOUT, int OIG, int NG,
          bool TIN>
__global__ __launch_bounds__(256) void dw_caps_kernel(
    const float* __restrict__ pose_in, const float* __restrict__ a_in,
    const float* __restrict__ Wt,
    const float* __restrict__ bu_p, const float* __restrict__ ba_p,
    float* __restrict__ pose_out, float* __restrict__ a_out) {
  constexpr int PAD = K / 2;
  constexpr int RA = (2 * (OIG - 1) + K < HIN) ? (2 * (OIG - 1) + K) : HIN;
  constexpr int TOT = OIG * WOUT * 16;
  constexpr int KM = (TOT + 255) / 256;
  __shared__ __align__(16) float tp[RA * WIN * 20];
  __shared__ float ta[RA * WIN];
  __shared__ __align__(16) float wt[K * K * 16];

  int t = threadIdx.x;
  int g = (NG > 1) ? (blockIdx.x % NG) : 0;
  int c = (blockIdx.x / NG) % BC;
  int b = blockIdx.x / (NG * BC);
  int oi_lo = g * OIG;
  int rlo = max(0, 2 * oi_lo - PAD);
  int rhi = min(HIN, 2 * (oi_lo + OIG - 1) - PAD + K);
  int nrows = rhi - rlo;

  for (int q = t; q < K * K * 16; q += 256) {
    int tap = q >> 4, lj = q & 15, l = lj >> 2, j = lj & 3;
    wt[tap * 16 + lj] = Wt[((size_t)tap * BC + c) * 16 + j * 4 + l];
  }
  for (int q = t; q < nrows * WIN; q += 256) {
    int row = q / WIN, col = q % WIN;
    if (TIN)
      ta[q] = a_in[(size_t)c * (32 * HIN * WIN) +
                   (size_t)(b * HIN + rlo + row) * WIN + col];
    else
      ta[q] = a_in[((size_t)((b * HIN + rlo + row) * WIN + col)) * BC + c];
  }
  for (int q = t; q < nrows * WIN * 4; q += 256) {
    int quad = q & 3, pc = q >> 2;
    int row = pc / WIN, col = pc % WIN;
    const float4 src = TIN
        ? *(const float4*)(pose_in +
              ((size_t)c * (32 * HIN * WIN) +
               (size_t)(b * HIN + rlo + row) * WIN + col) * 16 + quad * 4)
        : *(const float4*)(pose_in +
              (((size_t)((b * HIN + rlo + row) * WIN + col)) * BC + c) * 16 + quad * 4);
    *(float4*)(tp + (row * WIN + col) * 20 + quad * 4) = src;
  }
  __syncthreads();

  const int p = t & 15;
  const int ip = p >> 2, l = p & 3;
  const float* wtl = wt + l * 4;

  int ih0[KM], iw0[KM];
  float rsum[KM], acc[KM], acc2[KM];
#pragma unroll
  for (int k = 0; k < KM; ++k) {
    int s = t + k * 256;
    int pr = s >> 4;
    int oj = pr % WOUT;
    int oi = oi_lo + pr / WOUT;
    ih0[k] = 2 * oi - PAD;
    iw0[k] = 2 * oj - PAD;
    rsum[k] = 0.f;
    acc[k] = 0.f;
    acc2[k] = 0.f;
  }

#pragma unroll 1
  for (int ki = 0; ki < K; ++ki) {
    int rb[KM];
    bool vk[KM];
#pragma unroll
    for (int k = 0; k < KM; ++k) {
      int ih = ih0[k] + ki;
      vk[k] = (t + k * 256 < TOT) && (ih >= 0) && (ih < HIN);
      rb[k] = (ih - rlo) * WIN;
    }
#pragma unroll
    for (int kj = 0; kj < K; ++kj) {
      const float4 wr = *(const float4*)(wtl + (ki * K + kj) * 16);
#pragma unroll
      for (int k = 0; k < KM; ++k) {
        if (!vk[k]) continue;
        int iw = iw0[k] + kj;
        if (iw < 0 || iw >= WIN) continue;
        int idx = rb[k] + iw;
        float ak = ta[idx];
        const float4 pm = *(const float4*)(tp + idx * 20 + ip * 4);
        float v = pm.x * wr.x + pm.y * wr.y + pm.z * wr.z + pm.w * wr.w;
        rsum[k] += ak;
        float av = ak * v;
        acc[k] += av;
        acc2[k] += av * v;
      }
    }
  }

#pragma unroll 1
  for (int k = 0; k < KM; ++k) {
    int s = t + k * 256;
    if (s >= TOT) break;
    int pr = s >> 4;
    int oj = pr % WOUT;
    int oi = oi_lo + pr / WOUT;
    float inv = 1.f / (rsum[k] + EPS);
    float mu = acc[k] * inv;
    float S = rsum[k] * inv;
    float sg = acc2[k] * inv - mu * mu * (2.f - S);
    sg = fmaxf(sg, 0.f) + EPS;
    float hl = 0.5f * __logf(sg);
    float ls = hl;
    ls += __shfl_xor(ls, 1, 64);
    ls += __shfl_xor(ls, 2, 64);
    ls += __shfl_xor(ls, 4, 64);
    ls += __shfl_xor(ls, 8, 64);

    size_t obase = ((size_t)(b * HOUT + oi) * WOUT + oj) * BC + c;
    pose_out[obase * 16 + p] = mu;
    if (p == 0) {
      float cost = rsum[k] * (16.f * bu_p[0] + ls);
      a_out[obase] = sigmoidf(LAMBDA * (ba_p[0] - cost));
    }
  }
}

// ---------------------------------------------------------------------------
// 3) cc1 co-op EM (validated-pass)
// ---------------------------------------------------------------------------
__global__ __launch_bounds__(256) void cc_em_coop8_kernel(
    const float* __restrict__ pose_in, const float* __restrict__ a_arr,
    const float* __restrict__ Wt,
    const float* __restrict__ bu_p, const float* __restrict__ ba_p,
    float* __restrict__ pose_out, float* __restrict__ a_out) {
  __shared__ float red_s[2][2][2][64 * 9];   // [buf][prob][wavehalf] 18.4 KB
  int t = threadIdx.x;
  int w = t >> 6, lane = t & 63;
  int prob = w >> 1, wh = w & 1;
  int c = lane >> 2, q = lane & 3;
  int n = blockIdx.x * 2 + prob;

  float ain[4], rw[4], v[4][4];
  const float* pbase = pose_in + (size_t)n * 128;   // 8 caps x 16
#pragma unroll
  for (int i = 0; i < 4; ++i) {
    int b = wh * 4 + i;
    ain[i] = a_arr[(size_t)n * 8 + b];
    rw[i] = (1.f / 16.f) * ain[i];
    const float4 pm = *(const float4*)(pbase + b * 16 + q * 4);
    const float* wr = Wt + (b * 16 + c) * 16;
    const float4 r0 = *(const float4*)(wr + 0);
    const float4 r1 = *(const float4*)(wr + 4);
    const float4 r2 = *(const float4*)(wr + 8);
    const float4 r3 = *(const float4*)(wr + 12);
    v[i][0] = pm.x * r0.x + pm.y * r1.x + pm.z * r2.x + pm.w * r3.x;
    v[i][1] = pm.x * r0.y + pm.y * r1.y + pm.z * r2.y + pm.w * r3.y;
    v[i][2] = pm.x * r0.z + pm.y * r1.z + pm.z * r2.z + pm.w * r3.z;
    v[i][3] = pm.x * r0.w + pm.y * r1.w + pm.z * r2.w + pm.w * r3.w;
  }
  float bu = bu_p[c], ba = ba_p[c];

  float mu[4], inv2[4], lsum = 0.f, ao = 0.f;
#pragma unroll 1
  for (int it = 0; it < 3; ++it) {
    float psA = 0.f, psV[4] = {0, 0, 0, 0}, psV2[4] = {0, 0, 0, 0};
#pragma unroll
    for (int i = 0; i < 4; ++i) {
      psA += rw[i];
#pragma unroll
      for (int l = 0; l < 4; ++l) {
        float rv = rw[i] * v[i][l];
        psV[l] += rv;
        psV2[l] += rv * v[i][l];
      }
    }
    {
      float* rs = &red_s[it & 1][prob][wh][lane * 9];
      rs[0] = psA;
#pragma unroll
      for (int l = 0; l < 4; ++l) { rs[1 + l] = psV[l]; rs[5 + l] = psV2[l]; }
    }
    __syncthreads();
    float sA = 0.f, sV[4] = {0, 0, 0, 0}, sV2[4] = {0, 0, 0, 0};
#pragma unroll
    for (int w2 = 0; w2 < 2; ++w2) {
      const float* rr = &red_s[it & 1][prob][w2][lane * 9];
      sA += rr[0];
#pragma unroll
      for (int l = 0; l < 4; ++l) { sV[l] += rr[1 + l]; sV2[l] += rr[5 + l]; }
    }
    float inv = 1.f / (sA + EPS);
    float S = sA * inv;
    lsum = 0.f;
#pragma unroll
    for (int l = 0; l < 4; ++l) {
      mu[l] = sV[l] * inv;
      float sg = sV2[l] * inv - mu[l] * mu[l] * (2.f - S) + EPS;
      sg = fmaxf(sg, EPS);
      inv2[l] = 0.5f / sg;
      lsum += 0.5f * __logf(sg);
    }
    lsum += __shfl_xor(lsum, 1, 64);
    lsum += __shfl_xor(lsum, 2, 64);
    float cost = sA * (16.f * bu + lsum);
    ao = sigmoidf(LAMBDA * (ba - cost));

    if (it < 2) {
      float term[4];
#pragma unroll
      for (int i = 0; i < 4; ++i) {
        float s = 0.f;
#pragma unroll
        for (int l = 0; l < 4; ++l) {
          float d = v[i][l] - mu[l];
          s += d * d * inv2[l];
        }
        term[i] = s;
      }
#pragma unroll
      for (int i = 0; i < 4; ++i) {
        term[i] += __shfl_xor(term[i], 1, 64);
        term[i] += __shfl_xor(term[i], 2, 64);
      }
      float basec = __logf(EPS + ao) - lsum - 16.f * LN2PI_HALF;
      float lnap[4], mx[4], Z[4];
#pragma unroll
      for (int i = 0; i < 4; ++i) { lnap[i] = basec - term[i]; mx[i] = lnap[i]; }
#pragma unroll
      for (int m = 4; m < 64; m <<= 1)
#pragma unroll
        for (int i = 0; i < 4; ++i) mx[i] = fmaxf(mx[i], __shfl_xor(mx[i], m, 64));
#pragma unroll
      for (int i = 0; i < 4; ++i) { lnap[i] = __expf(lnap[i] - mx[i]); Z[i] = lnap[i]; }
#pragma unroll
      for (int m = 4; m < 64; m <<= 1)
#pragma unroll
        for (int i = 0; i < 4; ++i) Z[i] += __shfl_xor(Z[i], m, 64);
#pragma unroll
      for (int i = 0; i < 4; ++i) rw[i] = lnap[i] / Z[i] * ain[i];
    }
  }
  if (wh == 0) {
    *(float4*)(pose_out + (size_t)n * 256 + c * 16 + q * 4) =
        make_float4(mu[0], mu[1], mu[2], mu[3]);
    if (q == 0) a_out[(size_t)n * 16 + c] = ao;
  }
}

// ---------------------------------------------------------------------------
// 3b) cc2 co-op EM (validated)
// ---------------------------------------------------------------------------
__global__ __launch_bounds__(256) void cc_em_coop16_kernel(
    const float* __restrict__ pose_in, const float* __restrict__ a_arr,
    const float* __restrict__ Wt,
    const float* __restrict__ bu_p, const float* __restrict__ ba_p,
    float* __restrict__ pose_out, float* __restrict__ a_out) {
  __shared__ float red_s[2][4][64 * 9];   // 18.4 KB
  int t = threadIdx.x;
  int w = t >> 6, lane = t & 63;
  int c = lane >> 2, q = lane & 3;
  int n = blockIdx.x;

  float ain[4], rw[4], v[4][4];
  const float* pbase = pose_in + (size_t)n * 256;
#pragma unroll
  for (int i = 0; i < 4; ++i) {
    int b = w * 4 + i;
    ain[i] = a_arr[(size_t)n * 16 + b];
    rw[i] = (1.f / 16.f) * ain[i];
    const float4 pm = *(const float4*)(pbase + b * 16 + q * 4);
    const float* wr = Wt + (b * 16 + c) * 16;
    const float4 r0 = *(const float4*)(wr + 0);
    const float4 r1 = *(const float4*)(wr + 4);
    const float4 r2 = *(const float4*)(wr + 8);
    const float4 r3 = *(const float4*)(wr + 12);
    v[i][0] = pm.x * r0.x + pm.y * r1.x + pm.z * r2.x + pm.w * r3.x;
    v[i][1] = pm.x * r0.y + pm.y * r1.y + pm.z * r2.y + pm.w * r3.y;
    v[i][2] = pm.x * r0.z + pm.y * r1.z + pm.z * r2.z + pm.w * r3.z;
    v[i][3] = pm.x * r0.w + pm.y * r1.w + pm.z * r2.w + pm.w * r3.w;
  }
  float bu = bu_p[c], ba = ba_p[c];

  float mu[4], inv2[4], lsum = 0.f, ao = 0.f;
#pragma unroll 1
  for (int it = 0; it < 3; ++it) {
    float psA = 0.f, psV[4] = {0, 0, 0, 0}, psV2[4] = {0, 0, 0, 0};
#pragma unroll
    for (int i = 0; i < 4; ++i) {
      psA += rw[i];
#pragma unroll
      for (int l = 0; l < 4; ++l) {
        float rv = rw[i] * v[i][l];
        psV[l] += rv;
        psV2[l] += rv * v[i][l];
      }
    }
    {
      float* rs = &red_s[it & 1][w][lane * 9];
      rs[0] = psA;
#pragma unroll
      for (int l = 0; l < 4; ++l) { rs[1 + l] = psV[l]; rs[5 + l] = psV2[l]; }
    }
    __syncthreads();
    float sA = 0.f, sV[4] = {0, 0, 0, 0}, sV2[4] = {0, 0, 0, 0};
#pragma unroll
    for (int w2 = 0; w2 < 4; ++w2) {
      const float* rr = &red_s[it & 1][w2][lane * 9];
      sA += rr[0];
#pragma unroll
      for (int l = 0; l < 4; ++l) { sV[l] += rr[1 + l]; sV2[l] += rr[5 + l]; }
    }
    float inv = 1.f / (sA + EPS);
    float S = sA * inv;
    lsum = 0.f;
#pragma unroll
    for (int l = 0; l < 4; ++l) {
      mu[l] = sV[l] * inv;
      float sg = sV2[l] * inv - mu[l] * mu[l] * (2.f - S) + EPS;
      sg = fmaxf(sg, EPS);
      inv2[l] = 0.5f / sg;
      lsum += 0.5f * __logf(sg);
    }
    lsum += __shfl_xor(lsum, 1, 64);
    lsum += __shfl_xor(lsum, 2, 64);
    float cost = sA * (16.f * bu + lsum);
    ao = sigmoidf(LAMBDA * (ba - cost));

    if (it < 2) {
      float term[4];
#pragma unroll
      for (int i = 0; i < 4; ++i) {
        float s = 0.f;
#pragma unroll
        for (int l = 0; l < 4; ++l) {
          float d = v[i][l] - mu[l];
          s += d * d * inv2[l];
        }
        term[i] = s;
      }
#pragma unroll
      for (int i = 0; i < 4; ++i) {
        term[i] += __shfl_xor(term[i], 1, 64);
        term[i] += __shfl_xor(term[i], 2, 64);
      }
      float basec = __logf(EPS + ao) - lsum - 16.f * LN2PI_HALF;
      float lnap[4], mx[4], Z[4];
#pragma unroll
      for (int i = 0; i < 4; ++i) { lnap[i] = basec - term[i]; mx[i] = lnap[i]; }
#pragma unroll
      for (int m = 4; m < 64; m <<= 1)
#pragma unroll
        for (int i = 0; i < 4; ++i) mx[i] = fmaxf(mx[i], __shfl_xor(mx[i], m, 64));
#pragma unroll
      for (int i = 0; i < 4; ++i) { lnap[i] = __expf(lnap[i] - mx[i]); Z[i] = lnap[i]; }
#pragma unroll
      for (int m = 4; m < 64; m <<= 1)
#pragma unroll
        for (int i = 0; i < 4; ++i) Z[i] += __shfl_xor(Z[i], m, 64);
#pragma unroll
      for (int i = 0; i < 4; ++i) rw[i] = lnap[i] / Z[i] * ain[i];
    }
  }
  if (w == 0) {
    *(float4*)(pose_out + (size_t)n * 256 + c * 16 + q * 4) =
        make_float4(mu[0], mu[1], mu[2], mu[3]);
    if (q == 0) a_out[(size_t)n * 16 + c] = ao;
  }
}

// ---------------------------------------------------------------------------
// 4a) class caps M-step (round-10 validated)
// ---------------------------------------------------------------------------
__global__ __launch_bounds__(256) void cls_m_kernel(
    const float* __restrict__ pose5, const float* __restrict__ a5,
    const float* __restrict__ X, const float* __restrict__ W,
    const float* __restrict__ bu_p, const float* __restrict__ ba_p,
    float* __restrict__ mu_g, float* __restrict__ inv2_g,
    float* __restrict__ base_g, float* __restrict__ out,
    int first, int last) {
  int blk = blockIdx.x;                 // b*10 + c
  int c = blk % 10, b = blk / 10;
  int t = threadIdx.x;
  int lane = t & 63, wv = t >> 6;
  const float* pg = pose5 + (size_t)b * 16384;
  __shared__ float w_s[16][16];         // [jj][d]
  {
    int d = t & 15, jj = t >> 4;
    w_s[jj][d] = W[(d * 10 + c) * 16 + jj];
  }
  __syncthreads();
  const int d = t & 15;
  float wf[16];
#pragma unroll
  for (int jj = 0; jj < 16; ++jj) wf[jj] = w_s[jj][d];

  float sA = 0.f, sV[16], sV2[16];
#pragma unroll
  for (int p = 0; p < 16; ++p) { sV[p] = 0.f; sV2[p] = 0.f; }
#pragma unroll 1
  for (int rep = 0; rep < 4; ++rep) {
    int bi = rep * 256 + t;
    int pos = bi >> 4;
    float rw = first ? 0.1f * a5[(size_t)b * 1024 + bi]
                     : X[(size_t)blk * 1024 + bi];
    float ci = (float)(pos >> 3) * 0.125f;
    float cj = (float)(pos & 7) * 0.125f;
    const float* pp = pg + pos * 256 + d * 16;
    float pmr[16];
#pragma unroll
    for (int q = 0; q < 16; ++q) pmr[q] = pp[q];
    sA += rw;
#pragma unroll
    for (int p = 0; p < 16; ++p) {
      int ip = p >> 2, l = p & 3;
      float v = pmr[ip * 4 + 0] * wf[0 * 4 + l] + pmr[ip * 4 + 1] * wf[1 * 4 + l]
              + pmr[ip * 4 + 2] * wf[2 * 4 + l] + pmr[ip * 4 + 3] * wf[3 * 4 + l];
      if (p == 0) v += ci;
      else if (p == 1) v += cj;
      float rv = rw * v;
      sV[p] += rv;
      sV2[p] += rv * v;
    }
  }
#pragma unroll
  for (int off = 1; off < 64; off <<= 1) {
    sA += __shfl_xor(sA, off, 64);
#pragma unroll
    for (int p = 0; p < 16; ++p) {
      sV[p]  += __shfl_xor(sV[p],  off, 64);
      sV2[p] += __shfl_xor(sV2[p], off, 64);
    }
  }
  __shared__ float red[4][36];
  if (lane == 0) {
    red[wv][0] = sA;
#pragma unroll
    for (int p = 0; p < 16; ++p) { red[wv][1 + p] = sV[p]; red[wv][17 + p] = sV2[p]; }
  }
  __syncthreads();
  if (t < 16) {
    int p = t;
    float sAf  = red[0][0] + red[1][0] + red[2][0] + red[3][0];
    float sVf  = red[0][1+p] + red[1][1+p] + red[2][1+p] + red[3][1+p];
    float sV2f = red[0][17+p] + red[1][17+p] + red[2][17+p] + red[3][17+p];
    float inv = 1.f / (sAf + EPS);
    float S = sAf * inv;
    float mu = sVf * inv;
    float sg = sV2f * inv - mu * mu * (2.f - S) + EPS;
    sg = fmaxf(sg, EPS);
    mu_g[blk * 16 + p] = mu;
    inv2_g[blk * 16 + p] = 0.5f / sg;
    float hl = 0.5f * __logf(sg);
    float lsum = hl;
    lsum += __shfl_xor(lsum, 1, 64);
    lsum += __shfl_xor(lsum, 2, 64);
    lsum += __shfl_xor(lsum, 4, 64);
    lsum += __shfl_xor(lsum, 8, 64);
    if (p == 0) {
      float cost = sAf * (16.f * bu_p[c] + lsum);
      float ao = sigmoidf(LAMBDA * (ba_p[c] - cost));
      base_g[blk] = __logf(EPS + ao) - lsum - 16.f * LN2PI_HALF;
      if (last) out[blk] = ao;
    }
  }
}

// ---------------------------------------------------------------------------
// 4b) class caps E-step v2 (round-10 validated: 4 blocks/image x 256 thr)
// ---------------------------------------------------------------------------
__global__ __launch_bounds__(256) void cls_e_kernel(
    const float* __restrict__ pose5, const float* __restrict__ a5,
    const float* __restrict__ W,
    const float* __restrict__ mu_g, const float* __restrict__ inv2_g,
    const float* __restrict__ base_g, float* __restrict__ X) {
  int b = blockIdx.x >> 2;
  int t = threadIdx.x;
  int bi = ((blockIdx.x & 3) << 8) + t;
  const float* pg = pose5 + (size_t)b * 16384;
  __shared__ float w2[10][16][16];      // [c][jj][d]
  __shared__ float mu_s[160];
  __shared__ float inv2_s[160];
  __shared__ float base_s[10];
  for (int q = t; q < 2560; q += 256) {
    int dd = q & 15, jj = (q >> 4) & 15, c = q >> 8;
    w2[c][jj][dd] = W[(dd * 10 + c) * 16 + jj];
  }
  if (t < 160) { mu_s[t] = mu_g[b * 160 + t]; inv2_s[t] = inv2_g[b * 160 + t]; }
  if (t >= 160 && t < 170) base_s[t - 160] = base_g[b * 10 + (t - 160)];
  __syncthreads();

  int pos = bi >> 4, d2 = bi & 15;
  float ci = (float)(pos >> 3) * 0.125f;
  float cj = (float)(pos & 7) * 0.125f;
  const float* pp = pg + pos * 256 + d2 * 16;
  float pmr[16];
#pragma unroll
  for (int q = 0; q < 16; ++q) pmr[q] = pp[q];
  float lnap[10];
#pragma unroll 1
  for (int c = 0; c < 10; ++c) {
    float wf[16];
#pragma unroll
    for (int jj = 0; jj < 16; ++jj) wf[jj] = w2[c][jj][d2];
    float s = base_s[c];
#pragma unroll
    for (int p = 0; p < 16; ++p) {
      int ip = p >> 2, l = p & 3;
      float v = pmr[ip * 4 + 0] * wf[0 * 4 + l] + pmr[ip * 4 + 1] * wf[1 * 4 + l]
              + pmr[ip * 4 + 2] * wf[2 * 4 + l] + pmr[ip * 4 + 3] * wf[3 * 4 + l];
      if (p == 0) v += ci;
      else if (p == 1) v += cj;
      float dd = v - mu_s[c * 16 + p];
      s -= dd * dd * inv2_s[c * 16 + p];
    }
    lnap[c] = s;
  }
  float m = -1e30f;
#pragma unroll
  for (int c = 0; c < 10; ++c) m = fmaxf(m, lnap[c]);
  float Z = 0.f;
  float ex[10];
#pragma unroll
  for (int c = 0; c < 10; ++c) { ex[c] = __expf(lnap[c] - m); Z += ex[c]; }
  float invZ = a5[(size_t)b * 1024 + bi] / Z;
#pragma unroll
  for (int c = 0; c < 10; ++c) X[((size_t)(b * 10 + c)) * 1024 + bi] = ex[c] * invZ;
}

// ---------------------------------------------------------------------------
extern "C" void kernel_launch(void* const* d_in, const int* in_sizes, int n_in,
                              void* d_out, int out_size, void* d_ws, size_t ws_size,
                              hipStream_t stream) {
  const float* x       = (const float*)d_in[0];
  const float* conv1_w = (const float*)d_in[1];
  const float* conv1_b = (const float*)d_in[2];
  const float* pp_w    = (const float*)d_in[3];
  const float* pp_b    = (const float*)d_in[4];
  const float* pa_w    = (const float*)d_in[5];
  const float* pa_b    = (const float*)d_in[6];
  const float* dw1_w   = (const float*)d_in[7];
  const float* dw1_bu  = (const float*)d_in[8];
  const float* dw1_ba  = (const float*)d_in[9];
  const float* cc1_w   = (const float*)d_in[10];
  const float* cc1_bu  = (const float*)d_in[11];
  const float* cc1_ba  = (const float*)d_in[12];
  const float* dw2_w   = (const float*)d_in[13];
  const float* dw2_bu  = (const float*)d_in[14];
  const float* dw2_ba  = (const float*)d_in[15];
  const float* cc2_w   = (const float*)d_in[16];
  const float* cc2_bu  = (const float*)d_in[17];
  const float* cc2_ba  = (const float*)d_in[18];
  const float* cls_w   = (const float*)d_in[19];
  const float* cls_bu  = (const float*)d_in[20];
  const float* cls_ba  = (const float*)d_in[21];
  float* out = (float*)d_out;

  float* ws = (float*)d_ws;
  float* pose1 = ws;                  // 32*30*30*128 (channel-major: [8][28800][16])
  float* a1    = ws + 3686400;        // 32*30*30*8   (channel-major: [8][28800])
  float* pose2 = ws + 3916800;        // 32*15*15*128
  float* a2    = ws + 4838400;        // 32*15*15*8
  float* pose3 = ws;                  // 32*15*15*256 (aliases dead pose1)
  float* a3    = ws + 1843200;        // 32*15*15*16
  float* pose4 = ws + 1958400;        // 32*8*8*256
  float* a4    = ws + 2482688;        // 32*8*8*16
  float* pose5 = ws + 2515456;        // 32*8*8*256
  float* a5    = ws + 3039744;        // 32*8*8*16
  float* Xbuf  = ws + 3072512;        // 32*10*1024
  float* mu_g  = ws + 3400192;        // 32*160
  float* inv2_g= ws + 3405312;        // 32*160
  float* base_g= ws + 3410432;        // 32*10

  stem_primary_kernel<<<960, 256, 0, stream>>>(x, conv1_w, conv1_b,
                                               pp_w, pp_b, pa_w, pa_b, pose1, a1);
  dw_caps_kernel<7, 8, 30, 30, 15, 15, 3, 5, true><<<1280, 256, 0, stream>>>(
      pose1, a1, dw1_w, dw1_bu, dw1_ba, pose2, a2);
  cc_em_coop8_kernel<<<3600, 256, 0, stream>>>(pose2, a2, cc1_w, cc1_bu, cc1_ba,
                                               pose3, a3);
  dw_caps_kernel<5, 16, 15, 15, 8, 8, 2, 4, false><<<2048, 256, 0, stream>>>(
      pose3, a3, dw2_w, dw2_bu, dw2_ba, pose4, a4);
  cc_em_coop16_kernel<<<2048, 256, 0, stream>>>(pose4, a4, cc2_w, cc2_bu, cc2_ba,
                                                pose5, a5);
  cls_m_kernel<<<320, 256, 0, stream>>>(pose5, a5, Xbuf, cls_w, cls_bu, cls_ba,
                                        mu_g, inv2_g, base_g, out, 1, 0);
  cls_e_kernel<<<128, 256, 0, stream>>>(pose5, a5, cls_w, mu_g, inv2_g, base_g, Xbuf);
  cls_m_kernel<<<320, 256, 0, stream>>>(pose5, a5, Xbuf, cls_w, cls_bu, cls_ba,
                                        mu_g, inv2_g, base_g, out, 0, 0);
  cls_e_kernel<<<128, 256, 0, stream>>>(pose5, a5, cls_w, mu_g, inv2_g, base_g, Xbuf);
  cls_m_kernel<<<320, 256, 0, stream>>>(pose5, a5, Xbuf, cls_w, cls_bu, cls_ba,
                                        mu_g, inv2_g, base_g, out, 0, 1);
}